// Round 6
// baseline (5435.467 us; speedup 1.0000x reference)
//
#include <hip/hip_runtime.h>
#include <hip/hip_bf16.h>

#define L_ 2
#define H_ 1024
#define Z_ 256
#define B_ 128
#define SRC_ 64
#define K_ 48
#define BH_ (B_ * H_)
#define BZ_ (B_ * Z_)
#define BKZ_ ((size_t)B_ * K_ * Z_)
#define KA_ 2304   // lstm0 GEMM K: z(256) | attn(1024) | h0(1024)
#define KB_ 2048   // lstm1 GEMM K: h0n(1024) | h1(1024)

typedef unsigned short u16;
typedef __attribute__((ext_vector_type(8))) short short8;
typedef __attribute__((ext_vector_type(4))) float f32x4;

// ---------------- static device workspace ----------------
__device__ __align__(16) u16 g_Wc0[4096 * KA_];     // lstm0 weights [4h+g][KA]
__device__ __align__(16) u16 g_Wc1[4096 * KB_];     // lstm1 weights
__device__ __align__(16) u16 g_Wmq[512 * 1024];     // mu/sigma rows interleaved [2z+sel][1024]
__device__ __align__(16) u16 g_Woutb[1024 * 2048];  // Wout bf16
__device__ __align__(16) u16 g_WinT[1024 * 1024];   // Win transposed bf16
__device__ __align__(16) u16 g_ctxb[8192 * 1024];   // context bf16 [B*SRC][H]
__device__ __align__(16) u16 g_ctxW[8192 * 1024];   // ctx @ Wout[:, :H]^T
__device__ __align__(16) u16 g_ctxWin[8192 * 1024]; // ctx @ Win
__device__ __align__(16) u16 g_XA[2][B_ * KA_];     // lstm0 input (dbl-buf) [row-permuted]
__device__ __align__(16) u16 g_XB[2][B_ * KB_];     // lstm1 input
__device__ __align__(16) u16 g_XC[B_ * H_];         // h1n unfrozen (query / musig input)
__device__ float g_pb0[4096], g_pb1[4096], g_pbmq[512], g_wk0[4096];
__device__ float g_cs0[BH_], g_cs1[BH_];
// k-sort state: rows sorted by k descending; row r holds batch element g_perm[r]
__device__ int g_perm[B_], g_inv[B_], g_kr[B_], g_Mact[K_];

__device__ __forceinline__ float sigm(float x) { return 1.0f / (1.0f + expf(-x)); }
__device__ __forceinline__ u16 f2b(float f) {
    union { float f; unsigned u; } x; x.f = f;
    unsigned r = x.u + 0x7fffu + ((x.u >> 16) & 1u);
    return (u16)(r >> 16);
}
__device__ __forceinline__ float b2f(u16 s) {
    union { unsigned u; float f; } x; x.u = ((unsigned)s) << 16;
    return x.f;
}

// ---------------- sort rows by k descending; Mact[i] = #rows live at step i ------------
__global__ void k_sort(const int* __restrict__ kvec) {
    __shared__ int ks[B_];
    int t = threadIdx.x;
    if (t < B_) ks[t] = kvec[t];
    __syncthreads();
    if (t < B_) {
        int kb = ks[t], rank = 0;
        for (int j = 0; j < B_; ++j) { int kj = ks[j]; rank += (kj > kb) || (kj == kb && j < t); }
        g_perm[rank] = t; g_inv[t] = rank; g_kr[rank] = kb;
    }
    if (t < K_) { int c = 0; for (int j = 0; j < B_; ++j) c += (ks[j] > t); g_Mact[t] = c; }
}

__global__ void k_zero(float* __restrict__ out) {
    size_t n = 3 * BKZ_;
    for (size_t i = (size_t)blockIdx.x * 256 + threadIdx.x; i < n; i += (size_t)gridDim.x * 256)
        out[i] = 0.f;
}

// ---------------- prep kernels ----------------
__global__ void prep_wc0(const float* __restrict__ Wih, const float* __restrict__ Whh,
                         const float* __restrict__ bih, const float* __restrict__ bhh) {
    int n = blockIdx.x;                 // interleaved row: n = 4h+g
    int h = n >> 2, g = n & 3, r = g * 1024 + h;
    u16* row = g_Wc0 + (size_t)n * KA_;
    for (int j = threadIdx.x; j < KA_; j += 256) {
        float v = (j < 256) ? Wih[(size_t)r * 1281 + j]
                : (j < 1280) ? Wih[(size_t)r * 1281 + j + 1]
                             : Whh[(size_t)r * 1024 + (j - 1280)];
        row[j] = f2b(v);
    }
    if (threadIdx.x == 0) {
        g_wk0[n] = Wih[(size_t)r * 1281 + 256];
        g_pb0[n] = bih[r] + bhh[r];
    }
}

__global__ void prep_wc1(const float* __restrict__ Wih, const float* __restrict__ Whh,
                         const float* __restrict__ bih, const float* __restrict__ bhh) {
    int n = blockIdx.x;
    int h = n >> 2, g = n & 3, r = g * 1024 + h;
    u16* row = g_Wc1 + (size_t)n * KB_;
    for (int j = threadIdx.x; j < KB_; j += 256) {
        float v = (j < 1024) ? Wih[(size_t)r * 1024 + j] : Whh[(size_t)r * 1024 + (j - 1024)];
        row[j] = f2b(v);
    }
    if (threadIdx.x == 0) g_pb1[n] = bih[r] + bhh[r];
}

__global__ void prep_wmq(const float* __restrict__ muW, const float* __restrict__ mub,
                         const float* __restrict__ sgW, const float* __restrict__ sgb) {
    int n = blockIdx.x;                 // n = 2z+sel
    int z = n >> 1, sel = n & 1;
    const float* src = sel ? sgW : muW;
    u16* row = g_Wmq + (size_t)n * 1024;
    for (int j = threadIdx.x; j < 1024; j += 256) row[j] = f2b(src[(size_t)z * 1024 + j]);
    if (threadIdx.x == 0) g_pbmq[n] = sel ? sgb[z] : mub[z];
}

__global__ void prep_copy(const float* __restrict__ in, u16* __restrict__ out, int n) {
    for (int i = blockIdx.x * 256 + threadIdx.x; i < n; i += gridDim.x * 256)
        out[i] = f2b(in[i]);
}

__global__ void prep_winT(const float* __restrict__ Win) {
    __shared__ float t[32][33];
    int bx = blockIdx.x * 32, by = blockIdx.y * 32;
    int tx = threadIdx.x & 31, ty0 = threadIdx.x >> 5;
    for (int it = 0; it < 4; ++it) {
        int ty = ty0 + it * 8;
        t[ty][tx] = Win[(size_t)(by + ty) * 1024 + bx + tx];
    }
    __syncthreads();
    for (int it = 0; it < 4; ++it) {
        int ty = ty0 + it * 8;
        g_WinT[(size_t)(bx + ty) * 1024 + by + tx] = f2b(t[tx][ty]);
    }
}

// ---------------- K-split-4 MFMA quarter-loop (16x16 tile): wave w covers K-quarter ----
template <int K>
__device__ __forceinline__ void mmq(const u16* __restrict__ A, int sA,
                                    const u16* __restrict__ W, int sW,
                                    int m0, int n0, int w, int lane, f32x4& acc) {
    constexpr int KQ = K / 4;
    const int quad = lane >> 4, l16 = lane & 15;
    const u16* pa = A + (size_t)(m0 + l16) * sA + w * KQ + quad * 8;
    const u16* pw = W + (size_t)(n0 + l16) * sW + w * KQ + quad * 8;
#pragma unroll 4
    for (int k0 = 0; k0 < KQ; k0 += 32) {
        short8 a = *(const short8*)(const void*)(pa + k0);
        short8 b = *(const short8*)(const void*)(pw + k0);
        acc = __builtin_amdgcn_mfma_f32_16x16x32_bf16(a, b, acc, 0, 0, 0);
    }
}

// stage one wave's partial 16x16 C-tile into sm[w][16][17]
__device__ __forceinline__ void stage_q(float* sm, int w, int lane, const f32x4& acc) {
    int quad = lane >> 4, l16 = lane & 15;
#pragma unroll
    for (int r = 0; r < 4; ++r) sm[w * 272 + (quad * 4 + r) * 17 + l16] = acc[r];
}

// ---------------- K-split-4 MFMA, 32x32 tile: 4 independent acc chains per wave --------
template <int K>
__device__ __forceinline__ void mm32(const u16* __restrict__ A, int sA,
                                     const u16* __restrict__ W, int sW,
                                     int m0, int n0, int w, int lane, f32x4 acc[2][2]) {
    constexpr int KQ = K / 4;
    const int quad = lane >> 4, l16 = lane & 15;
    const u16* pa0 = A + (size_t)(m0 + l16) * sA + w * KQ + quad * 8;
    const u16* pa1 = pa0 + (size_t)16 * sA;
    const u16* pb0 = W + (size_t)(n0 + l16) * sW + w * KQ + quad * 8;
    const u16* pb1 = pb0 + (size_t)16 * sW;
#pragma unroll 4
    for (int k0 = 0; k0 < KQ; k0 += 32) {
        short8 a0 = *(const short8*)(const void*)(pa0 + k0);
        short8 a1 = *(const short8*)(const void*)(pa1 + k0);
        short8 b0 = *(const short8*)(const void*)(pb0 + k0);
        short8 b1 = *(const short8*)(const void*)(pb1 + k0);
        acc[0][0] = __builtin_amdgcn_mfma_f32_16x16x32_bf16(a0, b0, acc[0][0], 0, 0, 0);
        acc[0][1] = __builtin_amdgcn_mfma_f32_16x16x32_bf16(a0, b1, acc[0][1], 0, 0, 0);
        acc[1][0] = __builtin_amdgcn_mfma_f32_16x16x32_bf16(a1, b0, acc[1][0], 0, 0, 0);
        acc[1][1] = __builtin_amdgcn_mfma_f32_16x16x32_bf16(a1, b1, acc[1][1], 0, 0, 0);
    }
}

// ---------------- LSTM GEMM+cell, 32x32 tiles, grid 512 = 8 xcd x (4 mt x 16 nl) -------
template <int LAYER>
__global__ __launch_bounds__(256) void k_lstm(int step) {
    constexpr int K = (LAYER == 0) ? KA_ : KB_;
    const int p = step & 1;
    const u16* A = (LAYER == 0) ? g_XA[p] : g_XB[p];
    const u16* W = (LAYER == 0) ? g_Wc0 : g_Wc1;
    const float* pb = (LAYER == 0) ? g_pb0 : g_pb1;
    float* cs = (LAYER == 0) ? g_cs0 : g_cs1;
    const u16* stOld = (LAYER == 0) ? (g_XA[p] + 1280) : (g_XB[p] + 1024);
    u16* stNew = (LAYER == 0) ? (g_XA[1 - p] + 1280) : (g_XB[1 - p] + 1024);
    u16* hout = (LAYER == 0) ? g_XB[p] : g_XC;
    const int hoStride = (LAYER == 0) ? KB_ : 1024;

    const int tid = threadIdx.x, w = tid >> 6, lane = tid & 63;
    const int xcd = blockIdx.x & 7, loc = blockIdx.x >> 3;   // loc 0..63
    const int mt = loc & 3, nl = loc >> 2;                   // mt 0..3, nl 0..15
    const int m0 = mt * 32;
    const int n0 = (xcd * 16 + nl) * 32;                     // XCD owns fixed 512-col N-slice
    const int Mact = g_Mact[step];

    if (m0 >= Mact) {   // all 32 rows frozen: carry state (32 rows x 8 cols = 256 threads)
        const int r = m0 + (tid & 31), hg = (n0 >> 2) + (tid >> 5);
        stNew[(size_t)r * K + hg] = stOld[(size_t)r * K + hg];
        return;
    }

    __shared__ float smf[4 * 32 * 33];
    f32x4 acc[2][2] = {};
    mm32<K>(A, K, W, K, m0, n0, w, lane, acc);
    const int quad = lane >> 4, l16 = lane & 15;
#pragma unroll
    for (int i = 0; i < 2; ++i)
#pragma unroll
        for (int j = 0; j < 2; ++j)
#pragma unroll
            for (int r = 0; r < 4; ++r)
                smf[(w * 32 + i * 16 + quad * 4 + r) * 33 + j * 16 + l16] = acc[i][j][r];
    __syncthreads();
    // epilogue: 256 threads = 32 rows x 8 h-groups
    const int bl = tid & 31, hl = tid >> 5;
    const int r = m0 + bl;
    float g[4];
#pragma unroll
    for (int gg = 0; gg < 4; ++gg) {
        int c = hl * 4 + gg;
        float s = smf[bl * 33 + c] + smf[(32 + bl) * 33 + c] +
                  smf[(64 + bl) * 33 + c] + smf[(96 + bl) * 33 + c];
        g[gg] = s + pb[n0 + c];
    }
    const int kr = g_kr[r];
    if (LAYER == 0) {
        float kf = (float)kr;
#pragma unroll
        for (int gg = 0; gg < 4; ++gg) g[gg] += kf * g_wk0[n0 + hl * 4 + gg];
    }
    const int hg = (n0 >> 2) + hl;
    float cold = cs[r * 1024 + hg];
    float cn = sigm(g[1]) * cold + sigm(g[0]) * tanhf(g[2]);
    float hn = sigm(g[3]) * tanhf(cn);
    hout[(size_t)r * hoStride + hg] = f2b(hn);   // unfrozen output
    if (step < kr) {
        stNew[(size_t)r * K + hg] = f2b(hn);
        cs[r * 1024 + hg] = cn;
    } else {
        stNew[(size_t)r * K + hg] = stOld[(size_t)r * K + hg];
    }
}

// ---- mix2: musig (bid 0..255)  ||  FUSED attention (bid 256..383, no contract dispatch)
// Fused-attn block = (m16 group, 8-row half, 128-col slice). xcd = m16 for L2 locality:
// ctxWin/ctxW slices for those 16 batch rows (2 MB each) stay in the XCD's L2.
// scores+softmax computed block-locally (redundant across the 8 col-slices), q-GEMM
// full-K in registers (no cross-wave LDS reduce), align-contraction + tanh + XA write.
__global__ __launch_bounds__(256) void k_mix2(const float* __restrict__ eps,
                                              float* __restrict__ out, int step, int dp,
                                              int do_mu, int do_sc) {
    __shared__ float sm[1344];
    const int tid = threadIdx.x;
    const int Mact = g_Mact[step];
    if (blockIdx.x < 256) {
        if (!do_mu) return;
        const int w = tid >> 6, lane = tid & 63;
        const int xcd = blockIdx.x & 7, loc = blockIdx.x >> 3;  // loc 0..31
        const int mt = loc & 7, nl = loc >> 3;                  // nl 0..3
        const int m0 = mt * 16;
        const int n0 = (xcd * 4 + nl) * 16;                     // N=512 total
        if (m0 >= Mact) return;                                 // frozen tile: out prezeroed
        f32x4 acc = {0.f, 0.f, 0.f, 0.f};
        mmq<1024>(g_XC, 1024, g_Wmq, 1024, m0, n0, w, lane, acc);
        stage_q(sm, w, lane, acc);
        __syncthreads();
        if (tid < 128) {
            int bl = tid & 15, zl = tid >> 4;  // zl 0..7
            int r = m0 + bl;
            int c0 = 2 * zl, c1 = 2 * zl + 1;
            float mu = sm[bl * 17 + c0] + sm[272 + bl * 17 + c0] +
                       sm[544 + bl * 17 + c0] + sm[816 + bl * 17 + c0] + g_pbmq[n0 + c0];
            float sg = sm[bl * 17 + c1] + sm[272 + bl * 17 + c1] +
                       sm[544 + bl * 17 + c1] + sm[816 + bl * 17 + c1] + g_pbmq[n0 + c1];
            int zg = (n0 >> 1) + zl;
            int b = g_perm[r];
            float e = eps[((size_t)step * B_ + b) * Z_ + zg];
            float zn = mu + expf(sg) * e;
            g_XA[dp][(size_t)r * KA_ + zg] = f2b(zn);
            bool valid = step < g_kr[r];
            size_t o = ((size_t)b * K_ + step) * Z_ + zg;
            out[o] = valid ? zn : 0.f;
            out[BKZ_ + o] = valid ? mu : 0.f;
            out[2 * BKZ_ + o] = valid ? sg : 0.f;
        }
    } else {
        if (!do_sc) return;
        const int idx = blockIdx.x - 256;      // 0..127 ; (256+idx)&7 == idx&7
        const int m16 = idx & 7;               // == xcd: 16-row group
        const int half = (idx >> 3) & 1;       // which 8 rows this block owns
        const int j = idx >> 4;                // 0..7 : 128-col slice
        const int m0 = m16 * 16;
        if (m0 >= Mact) return;
        const int r0 = m0 + half * 8;
        const int n0 = j * 128;
        // ---- scores + softmax for rows r0..r0+7 (redundant across col-slices) ----
        const int row8 = tid >> 5, t32 = tid & 31;
        {
            const int r = r0 + row8;
            const int b = g_perm[r];
            const u16* q = g_XC + (size_t)r * 1024;
            const u16* cp = g_ctxWin + ((size_t)(b * SRC_ + t32)) * 1024;
            float d0 = 0.f, d1 = 0.f;
            for (int h = 0; h < 1024; h += 8) {
                short8 qv = *(const short8*)(const void*)(q + h);
                short8 v0 = *(const short8*)(const void*)(cp + h);
                short8 v1 = *(const short8*)(const void*)(cp + 32 * 1024 + h);
#pragma unroll
                for (int e = 0; e < 8; ++e) {
                    float qe = b2f(((const u16*)&qv)[e]);
                    d0 += qe * b2f(((const u16*)&v0)[e]);
                    d1 += qe * b2f(((const u16*)&v1)[e]);
                }
            }
            float mx = fmaxf(d0, d1);
            for (int o = 16; o; o >>= 1) mx = fmaxf(mx, __shfl_xor(mx, o, 32));
            float e0 = expf(d0 - mx), e1 = expf(d1 - mx);
            float sum = e0 + e1;
            for (int o = 16; o; o >>= 1) sum += __shfl_xor(sum, o, 32);
            float inv = 1.f / sum;
            sm[row8 * 64 + t32] = e0 * inv;
            sm[row8 * 64 + t32 + 32] = e1 * inv;
        }
        __syncthreads();
        // ---- q-GEMM: cred[16 rows][32 cols] per wave, full K in registers ----
        const int w = tid >> 6, lane = tid & 63;
        const int quad = lane >> 4, l16 = lane & 15;
        const int wn0 = n0 + w * 32;
        const u16* pa = g_XC + (size_t)(m0 + l16) * 1024 + quad * 8;
        const u16* pw0 = g_Woutb + 1024 + (size_t)(wn0 + l16) * 2048 + quad * 8;
        const u16* pw1 = pw0 + (size_t)16 * 2048;
        f32x4 ca = {0.f, 0.f, 0.f, 0.f}, cb = {0.f, 0.f, 0.f, 0.f};
#pragma unroll 4
        for (int k0 = 0; k0 < 1024; k0 += 32) {
            short8 av = *(const short8*)(const void*)(pa + k0);
            short8 b0 = *(const short8*)(const void*)(pw0 + k0);
            short8 b1 = *(const short8*)(const void*)(pw1 + k0);
            ca = __builtin_amdgcn_mfma_f32_16x16x32_bf16(av, b0, ca, 0, 0, 0);
            cb = __builtin_amdgcn_mfma_f32_16x16x32_bf16(av, b1, cb, 0, 0, 0);
        }
        // ---- contract + write (this block's 8 rows only; quads 2*half, 2*half+1) ----
        if ((quad >> 1) == half) {
#pragma unroll
            for (int sub = 0; sub < 2; ++sub) {
                const int c = wn0 + sub * 16 + l16;
                const f32x4& cc = sub ? cb : ca;
#pragma unroll
                for (int reg = 0; reg < 4; ++reg) {
                    const int lrow = quad * 4 + reg;          // 0..15 within tile
                    const int lr = lrow - half * 8;           // 0..7 local
                    const int rr = m0 + lrow;
                    const int b2 = g_perm[rr];
                    const u16* base = g_ctxW + ((size_t)b2 * SRC_) * 1024 + c;
                    float a = cc[reg];
#pragma unroll 8
                    for (int s = 0; s < SRC_; ++s)
                        a += sm[lr * 64 + s] * b2f(base[(size_t)s * 1024]);
                    g_XA[dp][(size_t)rr * KA_ + 256 + c] = f2b(tanhf(a));
                }
            }
        }
    }
}

// ---------------- init / final (row-permuted) ----------------
__global__ void k_init(const float* __restrict__ h0, const float* __restrict__ c0,
                       const float* __restrict__ z0) {
    int i = blockIdx.x * 256 + threadIdx.x;  // i < BH_
    int b = i >> 10, h = i & 1023;
    int r = g_inv[b];
    g_XA[0][(size_t)r * KA_ + 1280 + h] = f2b(h0[i]);            // h0 layer0 state
    g_XB[0][(size_t)r * KB_ + 1024 + h] = f2b(h0[BH_ + i]);      // h layer1 state
    g_XC[r * 1024 + h] = f2b(c0[BH_ + i]);                       // initial query c0[-1]
    g_cs0[r * 1024 + h] = c0[i];
    g_cs1[r * 1024 + h] = c0[BH_ + i];
    if (i < BZ_) {
        int bb = i >> 8, z = i & 255;
        g_XA[0][(size_t)g_inv[bb] * KA_ + z] = f2b(z0[i]);
    }
}

__global__ void k_final(float* __restrict__ out) {
    int i = blockIdx.x * 256 + threadIdx.x;  // i < BH_
    int b = i >> 10, h = i & 1023;
    int r = g_inv[b];
    float* hf = out + (size_t)3 * BKZ_;
    float* cf = hf + 2 * BH_;
    hf[i] = b2f(g_XA[0][(size_t)r * KA_ + 1280 + h]);
    hf[BH_ + i] = b2f(g_XB[0][(size_t)r * KB_ + 1024 + h]);
    cf[i] = g_cs0[r * 1024 + h];
    cf[BH_ + i] = g_cs1[r * 1024 + h];
}

// ---------------- fused prep GEMM, M-PARTITIONED across XCDs ---------------------------
// ctxW = ctx @ Wout[:, :1024]^T and ctxWin = ctx @ WinT^T, in one kernel.
// Each XCD owns 1024 A-rows (2 MB, L2-resident); weights stream once per XCD
// (W0 4MB + W1 2MB) instead of every XCD re-streaming all 16 MB of A.
// grid 2048 = 8 xcd x (32 jobs x 8 mtiles); consecutive blocks share a W n-slice.
__global__ __launch_bounds__(256) void k_prep3() {
    const int tid = threadIdx.x, w = tid >> 6, lane = tid & 63;
    const int quad = lane >> 4, l16 = lane & 15;
    const int xcd = blockIdx.x & 7, loc = blockIdx.x >> 3;   // loc 0..255
    const int mt8 = loc & 7, job = loc >> 3;                 // job 0..31
    const int sel = job >> 4, nt = job & 15;                 // sel: 0=ctxW, 1=ctxWin
    const u16* W = sel ? g_WinT : g_Woutb;
    const int sW = sel ? 1024 : 2048;
    u16* Out = sel ? g_ctxWin : g_ctxW;
    const int n0 = nt * 64;
    const int mb = (xcd * 8 + mt8) * 128 + w * 32;           // XCD-owned 1024-row M slice
    f32x4 acc[2][4] = {};
    const u16* pa0 = g_ctxb + (size_t)(mb + l16) * 1024 + quad * 8;
    const u16* pa1 = pa0 + (size_t)16 * 1024;
    const u16* pw = W + (size_t)(n0 + l16) * sW + quad * 8;
#pragma unroll 2
    for (int k0 = 0; k0 < 1024; k0 += 32) {
        short8 a0 = *(const short8*)(const void*)(pa0 + k0);
        short8 a1 = *(const short8*)(const void*)(pa1 + k0);
#pragma unroll
        for (int j = 0; j < 4; ++j) {
            short8 b = *(const short8*)(const void*)(pw + (size_t)j * 16 * sW + k0);
            acc[0][j] = __builtin_amdgcn_mfma_f32_16x16x32_bf16(a0, b, acc[0][j], 0, 0, 0);
            acc[1][j] = __builtin_amdgcn_mfma_f32_16x16x32_bf16(a1, b, acc[1][j], 0, 0, 0);
        }
    }
#pragma unroll
    for (int i = 0; i < 2; ++i)
#pragma unroll
        for (int j = 0; j < 4; ++j)
#pragma unroll
            for (int r = 0; r < 4; ++r)
                Out[(size_t)(mb + i * 16 + quad * 4 + r) * 1024 + n0 + j * 16 + l16] =
                    f2b(acc[i][j][r]);
}

extern "C" void kernel_launch(void* const* d_in, const int* in_sizes, int n_in,
                              void* d_out, int out_size, void* d_ws, size_t ws_size,
                              hipStream_t stream) {
    (void)in_sizes; (void)n_in; (void)out_size; (void)d_ws; (void)ws_size;
    const float* h0 = (const float*)d_in[0];
    const float* c0 = (const float*)d_in[1];
    const float* ctx = (const float*)d_in[2];
    const float* z0 = (const float*)d_in[3];
    const int* kvec = (const int*)d_in[4];
    const float* eps = (const float*)d_in[5];
    const float* Wih0 = (const float*)d_in[6];
    const float* Whh0 = (const float*)d_in[7];
    const float* bih0 = (const float*)d_in[8];
    const float* bhh0 = (const float*)d_in[9];
    const float* Wih1 = (const float*)d_in[10];
    const float* Whh1 = (const float*)d_in[11];
    const float* bih1 = (const float*)d_in[12];
    const float* bhh1 = (const float*)d_in[13];
    const float* Win = (const float*)d_in[14];
    const float* Wout = (const float*)d_in[15];
    const float* muW = (const float*)d_in[16];
    const float* mub = (const float*)d_in[17];
    const float* sgW = (const float*)d_in[18];
    const float* sgb = (const float*)d_in[19];
    float* out = (float*)d_out;

    dim3 blk(256);
    // ---- one-time prep ----
    k_sort<<<1, 128, 0, stream>>>(kvec);
    k_zero<<<2048, blk, 0, stream>>>(out);
    prep_wc0<<<4096, blk, 0, stream>>>(Wih0, Whh0, bih0, bhh0);
    prep_wc1<<<4096, blk, 0, stream>>>(Wih1, Whh1, bih1, bhh1);
    prep_wmq<<<512, blk, 0, stream>>>(muW, mub, sgW, sgb);
    {
        u16* woutb; hipGetSymbolAddress((void**)&woutb, HIP_SYMBOL(g_Woutb));
        u16* ctxb; hipGetSymbolAddress((void**)&ctxb, HIP_SYMBOL(g_ctxb));
        prep_copy<<<2048, blk, 0, stream>>>(Wout, woutb, 1024 * 2048);
        prep_copy<<<8192, blk, 0, stream>>>(ctx, ctxb, 8192 * 1024);
        prep_winT<<<dim3(32, 32), blk, 0, stream>>>(Win);
        // ctxW = ctx @ Wout[:, :1024]^T ; ctxWin = ctx @ Win   (fused, M-partitioned)
        k_prep3<<<2048, blk, 0, stream>>>();
    }
    // ---- init state (row-permuted) + initial attention (q = c0[-1]) ----
    k_init<<<BH_ / 256, blk, 0, stream>>>(h0, c0, z0);
    k_mix2<<<384, blk, 0, stream>>>(eps, out, 0, 0, 0, 1);    // fused attn0 -> XA[0]

    // ---- 48 steps, 3 dispatches each ----
    for (int i = 0; i < K_; ++i) {
        k_lstm<0><<<512, blk, 0, stream>>>(i);
        k_lstm<1><<<512, blk, 0, stream>>>(i);
        const int more = (i + 1 < K_) ? 1 : 0;
        k_mix2<<<384, blk, 0, stream>>>(eps, out, i, (i + 1) & 1, 1, more);
    }
    // K_=48 even -> final states in parity-0 buffers
    k_final<<<BH_ / 256, blk, 0, stream>>>(out);
}

// Round 7
// 3086.526 us; speedup vs baseline: 1.7610x; 1.7610x over previous
//
#include <hip/hip_runtime.h>
#include <hip/hip_bf16.h>

#define L_ 2
#define H_ 1024
#define Z_ 256
#define B_ 128
#define SRC_ 64
#define K_ 48
#define BH_ (B_ * H_)
#define BZ_ (B_ * Z_)
#define BKZ_ ((size_t)B_ * K_ * Z_)
#define KA_ 2304   // lstm0 GEMM K: z(256) | attn(1024) | h0(1024)
#define KB_ 2048   // lstm1 GEMM K: h0n(1024) | h1(1024)

typedef unsigned short u16;
typedef __attribute__((ext_vector_type(8))) short short8;
typedef __attribute__((ext_vector_type(4))) float f32x4;

// ---------------- static device workspace ----------------
__device__ __align__(16) u16 g_Wc0[4096 * KA_];     // lstm0 weights [4h+g][KA]
__device__ __align__(16) u16 g_Wc1[4096 * KB_];     // lstm1 weights
__device__ __align__(16) u16 g_Wmq[512 * 1024];     // mu/sigma rows interleaved [2z+sel][1024]
__device__ __align__(16) u16 g_Woutb[1024 * 2048];  // Wout bf16
__device__ __align__(16) u16 g_WinT[1024 * 1024];   // Win transposed bf16
__device__ __align__(16) u16 g_ctxb[8192 * 1024];   // context bf16 [B*SRC][H]
__device__ __align__(16) u16 g_ctxW[8192 * 1024];   // ctx @ Wout[:, :H]^T
__device__ __align__(16) u16 g_ctxWin[8192 * 1024]; // ctx @ Win
__device__ __align__(16) u16 g_XA[2][B_ * KA_];     // lstm0 input (dbl-buf) [row-permuted]
__device__ __align__(16) u16 g_XB[2][B_ * KB_];     // lstm1 input
__device__ __align__(16) u16 g_XC[B_ * H_];         // h1n unfrozen (query / musig input)
__device__ float g_pb0[4096], g_pb1[4096], g_pbmq[512], g_wk0[4096];
__device__ float g_cs0[BH_], g_cs1[BH_], g_align[B_ * SRC_];
__device__ float g_cred[B_ * H_];                   // attn q-GEMM staging (fp32)
// k-sort state: rows sorted by k descending; row r holds batch element g_perm[r]
__device__ int g_perm[B_], g_inv[B_], g_kr[B_], g_Mact[K_];

__device__ __forceinline__ float sigm(float x) { return 1.0f / (1.0f + expf(-x)); }
__device__ __forceinline__ u16 f2b(float f) {
    union { float f; unsigned u; } x; x.f = f;
    unsigned r = x.u + 0x7fffu + ((x.u >> 16) & 1u);
    return (u16)(r >> 16);
}
__device__ __forceinline__ float b2f(u16 s) {
    union { unsigned u; float f; } x; x.u = ((unsigned)s) << 16;
    return x.f;
}

// ---------------- ONE fused prep dispatch: all independent prep work -------------------
// sections: wc0[0,4096) | wc1[4096,8192) | wmq[8192,8704) | winT[8704,9728) |
//           sort{9728} | copyWout[9729,11777) | copyCtx[11777,19969) | zero[19969,22017)
#define PREPALL_NBLK_ 22017
__global__ __launch_bounds__(256) void k_prepall(
        const float* __restrict__ Wih0, const float* __restrict__ Whh0,
        const float* __restrict__ bih0, const float* __restrict__ bhh0,
        const float* __restrict__ Wih1, const float* __restrict__ Whh1,
        const float* __restrict__ bih1, const float* __restrict__ bhh1,
        const float* __restrict__ muW, const float* __restrict__ mub,
        const float* __restrict__ sgW, const float* __restrict__ sgb,
        const float* __restrict__ Win, const float* __restrict__ Wout,
        const float* __restrict__ ctx, const int* __restrict__ kvec,
        float* __restrict__ out) {
    __shared__ float shf[32 * 33];
    const int bid = blockIdx.x, tid = threadIdx.x;
    if (bid < 4096) {                         // ---- wc0 ----
        int n = bid, h = n >> 2, g = n & 3, r = g * 1024 + h;
        u16* row = g_Wc0 + (size_t)n * KA_;
        for (int j = tid; j < KA_; j += 256) {
            float v = (j < 256) ? Wih0[(size_t)r * 1281 + j]
                    : (j < 1280) ? Wih0[(size_t)r * 1281 + j + 1]
                                 : Whh0[(size_t)r * 1024 + (j - 1280)];
            row[j] = f2b(v);
        }
        if (tid == 0) {
            g_wk0[n] = Wih0[(size_t)r * 1281 + 256];
            g_pb0[n] = bih0[r] + bhh0[r];
        }
    } else if (bid < 8192) {                  // ---- wc1 ----
        int n = bid - 4096, h = n >> 2, g = n & 3, r = g * 1024 + h;
        u16* row = g_Wc1 + (size_t)n * KB_;
        for (int j = tid; j < KB_; j += 256) {
            float v = (j < 1024) ? Wih1[(size_t)r * 1024 + j]
                                 : Whh1[(size_t)r * 1024 + (j - 1024)];
            row[j] = f2b(v);
        }
        if (tid == 0) g_pb1[n] = bih1[r] + bhh1[r];
    } else if (bid < 8704) {                  // ---- wmq ----
        int n = bid - 8192, z = n >> 1, sel = n & 1;
        const float* src = sel ? sgW : muW;
        u16* row = g_Wmq + (size_t)n * 1024;
        for (int j = tid; j < 1024; j += 256) row[j] = f2b(src[(size_t)z * 1024 + j]);
        if (tid == 0) g_pbmq[n] = sel ? sgb[z] : mub[z];
    } else if (bid < 9728) {                  // ---- winT ----
        int loc = bid - 8704;
        int bx = (loc & 31) * 32, by = (loc >> 5) * 32;
        int tx = tid & 31, ty0 = tid >> 5;
        for (int it = 0; it < 4; ++it) {
            int ty = ty0 + it * 8;
            shf[ty * 33 + tx] = Win[(size_t)(by + ty) * 1024 + bx + tx];
        }
        __syncthreads();
        for (int it = 0; it < 4; ++it) {
            int ty = ty0 + it * 8;
            g_WinT[(size_t)(bx + ty) * 1024 + by + tx] = f2b(shf[tx * 33 + ty]);
        }
    } else if (bid == 9728) {                 // ---- sort ----
        int* ks = (int*)shf;
        if (tid < B_) ks[tid] = kvec[tid];
        __syncthreads();
        if (tid < B_) {
            int kb = ks[tid], rank = 0;
            for (int j = 0; j < B_; ++j) {
                int kj = ks[j];
                rank += (kj > kb) || (kj == kb && j < tid);
            }
            g_perm[rank] = tid; g_inv[tid] = rank; g_kr[rank] = kb;
        }
        if (tid < K_) {
            int c = 0;
            for (int j = 0; j < B_; ++j) c += (ks[j] > tid);
            g_Mact[tid] = c;
        }
    } else if (bid < 11777) {                 // ---- copy Wout -> bf16 ----
        int loc = bid - 9729;
        const int n = 1024 * 2048;
        for (int i = loc * 256 + tid; i < n; i += 2048 * 256)
            g_Woutb[i] = f2b(Wout[i]);
    } else if (bid < 19969) {                 // ---- copy ctx -> bf16 ----
        int loc = bid - 11777;
        const int n = 8192 * 1024;
        for (int i = loc * 256 + tid; i < n; i += 8192 * 256)
            g_ctxb[i] = f2b(ctx[i]);
    } else {                                  // ---- zero out[0..3*BKZ) ----
        int loc = bid - 19969;
        size_t n = 3 * BKZ_;
        for (size_t i = (size_t)loc * 256 + tid; i < n; i += (size_t)2048 * 256)
            out[i] = 0.f;
    }
}

// ---------------- K-split-4 MFMA quarter-loop (16x16 tile): wave w covers K-quarter ----
template <int K>
__device__ __forceinline__ void mmq(const u16* __restrict__ A, int sA,
                                    const u16* __restrict__ W, int sW,
                                    int m0, int n0, int w, int lane, f32x4& acc) {
    constexpr int KQ = K / 4;
    const int quad = lane >> 4, l16 = lane & 15;
    const u16* pa = A + (size_t)(m0 + l16) * sA + w * KQ + quad * 8;
    const u16* pw = W + (size_t)(n0 + l16) * sW + w * KQ + quad * 8;
#pragma unroll 4
    for (int k0 = 0; k0 < KQ; k0 += 32) {
        short8 a = *(const short8*)(const void*)(pa + k0);
        short8 b = *(const short8*)(const void*)(pw + k0);
        acc = __builtin_amdgcn_mfma_f32_16x16x32_bf16(a, b, acc, 0, 0, 0);
    }
}

// stage one wave's partial 16x16 C-tile into sm[w][16][17]
__device__ __forceinline__ void stage_q(float* sm, int w, int lane, const f32x4& acc) {
    int quad = lane >> 4, l16 = lane & 15;
#pragma unroll
    for (int r = 0; r < 4; ++r) sm[w * 272 + (quad * 4 + r) * 17 + l16] = acc[r];
}

// ---------------- K-split-4 MFMA, 32x32 tile: 4 independent acc chains per wave --------
template <int K>
__device__ __forceinline__ void mm32(const u16* __restrict__ A, int sA,
                                     const u16* __restrict__ W, int sW,
                                     int m0, int n0, int w, int lane, f32x4 acc[2][2]) {
    constexpr int KQ = K / 4;
    const int quad = lane >> 4, l16 = lane & 15;
    const u16* pa0 = A + (size_t)(m0 + l16) * sA + w * KQ + quad * 8;
    const u16* pa1 = pa0 + (size_t)16 * sA;
    const u16* pb0 = W + (size_t)(n0 + l16) * sW + w * KQ + quad * 8;
    const u16* pb1 = pb0 + (size_t)16 * sW;
#pragma unroll 4
    for (int k0 = 0; k0 < KQ; k0 += 32) {
        short8 a0 = *(const short8*)(const void*)(pa0 + k0);
        short8 a1 = *(const short8*)(const void*)(pa1 + k0);
        short8 b0 = *(const short8*)(const void*)(pb0 + k0);
        short8 b1 = *(const short8*)(const void*)(pb1 + k0);
        acc[0][0] = __builtin_amdgcn_mfma_f32_16x16x32_bf16(a0, b0, acc[0][0], 0, 0, 0);
        acc[0][1] = __builtin_amdgcn_mfma_f32_16x16x32_bf16(a0, b1, acc[0][1], 0, 0, 0);
        acc[1][0] = __builtin_amdgcn_mfma_f32_16x16x32_bf16(a1, b0, acc[1][0], 0, 0, 0);
        acc[1][1] = __builtin_amdgcn_mfma_f32_16x16x32_bf16(a1, b1, acc[1][1], 0, 0, 0);
    }
}

// ---------------- LSTM GEMM+cell, 32x32 tiles, grid 512 = 8 xcd x (4 mt x 16 nl) -------
template <int LAYER>
__global__ __launch_bounds__(256) void k_lstm(int step) {
    constexpr int K = (LAYER == 0) ? KA_ : KB_;
    const int p = step & 1;
    const u16* A = (LAYER == 0) ? g_XA[p] : g_XB[p];
    const u16* W = (LAYER == 0) ? g_Wc0 : g_Wc1;
    const float* pb = (LAYER == 0) ? g_pb0 : g_pb1;
    float* cs = (LAYER == 0) ? g_cs0 : g_cs1;
    const u16* stOld = (LAYER == 0) ? (g_XA[p] + 1280) : (g_XB[p] + 1024);
    u16* stNew = (LAYER == 0) ? (g_XA[1 - p] + 1280) : (g_XB[1 - p] + 1024);
    u16* hout = (LAYER == 0) ? g_XB[p] : g_XC;
    const int hoStride = (LAYER == 0) ? KB_ : 1024;

    const int tid = threadIdx.x, w = tid >> 6, lane = tid & 63;
    const int xcd = blockIdx.x & 7, loc = blockIdx.x >> 3;   // loc 0..63
    const int mt = loc & 3, nl = loc >> 2;                   // mt 0..3, nl 0..15
    const int m0 = mt * 32;
    const int n0 = (xcd * 16 + nl) * 32;                     // XCD owns fixed 512-col N-slice
    const int Mact = g_Mact[step];

    if (m0 >= Mact) {   // all 32 rows frozen: carry state (32 rows x 8 cols = 256 threads)
        const int r = m0 + (tid & 31), hg = (n0 >> 2) + (tid >> 5);
        stNew[(size_t)r * K + hg] = stOld[(size_t)r * K + hg];
        return;
    }

    __shared__ float smf[4 * 32 * 33];
    f32x4 acc[2][2] = {};
    mm32<K>(A, K, W, K, m0, n0, w, lane, acc);
    const int quad = lane >> 4, l16 = lane & 15;
#pragma unroll
    for (int i = 0; i < 2; ++i)
#pragma unroll
        for (int j = 0; j < 2; ++j)
#pragma unroll
            for (int r = 0; r < 4; ++r)
                smf[(w * 32 + i * 16 + quad * 4 + r) * 33 + j * 16 + l16] = acc[i][j][r];
    __syncthreads();
    // epilogue: 256 threads = 32 rows x 8 h-groups
    const int bl = tid & 31, hl = tid >> 5;
    const int r = m0 + bl;
    float g[4];
#pragma unroll
    for (int gg = 0; gg < 4; ++gg) {
        int c = hl * 4 + gg;
        float s = smf[bl * 33 + c] + smf[(32 + bl) * 33 + c] +
                  smf[(64 + bl) * 33 + c] + smf[(96 + bl) * 33 + c];
        g[gg] = s + pb[n0 + c];
    }
    const int kr = g_kr[r];
    if (LAYER == 0) {
        float kf = (float)kr;
#pragma unroll
        for (int gg = 0; gg < 4; ++gg) g[gg] += kf * g_wk0[n0 + hl * 4 + gg];
    }
    const int hg = (n0 >> 2) + hl;
    float cold = cs[r * 1024 + hg];
    float cn = sigm(g[1]) * cold + sigm(g[0]) * tanhf(g[2]);
    float hn = sigm(g[3]) * tanhf(cn);
    hout[(size_t)r * hoStride + hg] = f2b(hn);   // unfrozen output
    if (step < kr) {
        stNew[(size_t)r * K + hg] = f2b(hn);
        cs[r * 1024 + hg] = cn;
    } else {
        stNew[(size_t)r * K + hg] = stOld[(size_t)r * K + hg];
    }
}

// ---- mix: musig (0..255) | scores+softmax (256..383) | attn q-GEMM -> cred (384..895) --
__global__ __launch_bounds__(256) void k_mix(const float* __restrict__ eps,
                                             float* __restrict__ out, int step,
                                             int do_mu, int do_sc) {
    __shared__ float sm[1344];
    const int tid = threadIdx.x;
    const int Mact = g_Mact[step];
    if (blockIdx.x < 256) {
        if (!do_mu) return;
        const int w = tid >> 6, lane = tid & 63;
        const int xcd = blockIdx.x & 7, loc = blockIdx.x >> 3;  // loc 0..31
        const int mt = loc & 7, nl = loc >> 3;                  // nl 0..3
        const int m0 = mt * 16;
        const int n0 = (xcd * 4 + nl) * 16;                     // N=512 total
        if (m0 >= Mact) return;                                 // frozen tile: out prezeroed
        f32x4 acc = {0.f, 0.f, 0.f, 0.f};
        mmq<1024>(g_XC, 1024, g_Wmq, 1024, m0, n0, w, lane, acc);
        stage_q(sm, w, lane, acc);
        __syncthreads();
        if (tid < 128) {
            int bl = tid & 15, zl = tid >> 4;  // zl 0..7
            int r = m0 + bl;
            int c0 = 2 * zl, c1 = 2 * zl + 1;
            float mu = sm[bl * 17 + c0] + sm[272 + bl * 17 + c0] +
                       sm[544 + bl * 17 + c0] + sm[816 + bl * 17 + c0] + g_pbmq[n0 + c0];
            float sg = sm[bl * 17 + c1] + sm[272 + bl * 17 + c1] +
                       sm[544 + bl * 17 + c1] + sm[816 + bl * 17 + c1] + g_pbmq[n0 + c1];
            int zg = (n0 >> 1) + zl;
            int b = g_perm[r];
            float e = eps[((size_t)step * B_ + b) * Z_ + zg];
            float zn = mu + expf(sg) * e;
            g_XA[(step + 1) & 1][(size_t)r * KA_ + zg] = f2b(zn);
            bool valid = step < g_kr[r];
            size_t o = ((size_t)b * K_ + step) * Z_ + zg;
            out[o] = valid ? zn : 0.f;
            out[BKZ_ + o] = valid ? mu : 0.f;
            out[2 * BKZ_ + o] = valid ? sg : 0.f;
        }
    } else if (blockIdx.x < 384) {
        if (!do_sc) return;
        const int r = blockIdx.x - 256;      // sorted row
        if (r >= Mact) return;
        float* qf = sm;                      // [1024]
        float* parts = sm + 1024;            // [64][4]
        for (int i = tid; i < 1024; i += 256) qf[i] = b2f(g_XC[r * 1024 + i]);
        __syncthreads();
        int s = tid >> 2, part = tid & 3;
        const int b = g_perm[r];
        const u16* row = g_ctxWin + ((size_t)(b * SRC_ + s)) * 1024 + part * 256;
        float pacc = 0.f;
        for (int j = 0; j < 256; j += 8) {
            short8 v = *(const short8*)(const void*)(row + j);
#pragma unroll
            for (int t = 0; t < 8; ++t) pacc += qf[part * 256 + j + t] * b2f(((u16*)&v)[t]);
        }
        parts[s * 4 + part] = pacc;
        __syncthreads();
        if (tid < 64) {
            float v = parts[tid * 4] + parts[tid * 4 + 1] + parts[tid * 4 + 2] + parts[tid * 4 + 3];
            float mx = v;
            for (int o = 32; o; o >>= 1) mx = fmaxf(mx, __shfl_xor(mx, o, 64));
            float e = expf(v - mx), sum = e;
            for (int o = 32; o; o >>= 1) sum += __shfl_xor(sum, o, 64);
            g_align[r * SRC_ + tid] = e / sum;
        }
    } else {
        if (!do_sc) return;
        const int w = tid >> 6, lane = tid & 63;
        const int t = blockIdx.x - 384;           // 0..511
        const int xcd = t & 7, loc = t >> 3;      // loc 0..63
        const int mt = loc & 7, nl = loc >> 3;    // nl 0..7
        const int m0 = mt * 16;
        const int n0 = (xcd * 8 + nl) * 16;       // N=1024 total
        if (m0 >= Mact) return;
        f32x4 acc = {0.f, 0.f, 0.f, 0.f};
        mmq<1024>(g_XC, 1024, g_Woutb + 1024, 2048, m0, n0, w, lane, acc);
        stage_q(sm, w, lane, acc);
        __syncthreads();
        int bl = tid >> 4, hc = tid & 15;
        float cred = sm[bl * 17 + hc] + sm[272 + bl * 17 + hc] +
                     sm[544 + bl * 17 + hc] + sm[816 + bl * 17 + hc];
        g_cred[(size_t)(m0 + bl) * 1024 + n0 + hc] = cred;
    }
}

// ---- attn align-contraction: light, 512 blocks of 16 rows x 16 cols; writes XA[dp] ----
__global__ __launch_bounds__(256) void k_contract(int dp, int step) {
    __shared__ float sm[16 * SRC_];
    const int tid = threadIdx.x;
    const int xcd = blockIdx.x & 7, loc = blockIdx.x >> 3;
    const int mt = loc & 7, nl = loc >> 3;
    const int m0 = mt * 16;
    const int n0 = (xcd * 8 + nl) * 16;
    if (m0 >= g_Mact[step]) return;
    for (int i = tid; i < 16 * SRC_; i += 256)
        sm[i] = g_align[(m0 + (i >> 6)) * SRC_ + (i & 63)];
    __syncthreads();
    int bl = tid >> 4, hc = tid & 15;
    int r = m0 + bl;
    const int b = g_perm[r];
    const u16* base = g_ctxW + ((size_t)b * SRC_) * 1024 + n0 + hc;
    float a = g_cred[(size_t)r * 1024 + n0 + hc];
#pragma unroll 8
    for (int s = 0; s < SRC_; ++s) a += sm[bl * 64 + s] * b2f(base[(size_t)s * 1024]);
    g_XA[dp][(size_t)r * KA_ + 256 + n0 + hc] = f2b(tanhf(a));
}

// ---------------- merged prep GEMMs + init: one dispatch, 2560 blocks ------------------
// blocks 0..2047: the two proven 128x64-tile prep GEMMs, interleaved (sel = bid&1) so
// both jobs are co-resident (they share ctxb reads in L2). blocks 2048..2559: k_init.
__global__ __launch_bounds__(256) void k_gemminit(const float* __restrict__ h0,
                                                  const float* __restrict__ c0,
                                                  const float* __restrict__ z0) {
    const int bid = blockIdx.x, tid = threadIdx.x;
    if (bid < 2048) {
        const int sel = bid & 1;             // 0: ctxW = ctx@Wout'; 1: ctxWin = ctx@WinT'
        const int vb = bid >> 1;             // 0..1023, the proven 1-D layout
        const u16* W = sel ? g_WinT : g_Woutb;
        const int sW = sel ? 1024 : 2048;
        u16* Out = sel ? g_ctxWin : g_ctxW;
        const int w = tid >> 6, lane = tid & 63;
        const int quad = lane >> 4, l16 = lane & 15;
        const int xcd = vb & 7, loc = vb >> 3;               // loc 0..127
        const int n0 = (xcd * 2 + (loc & 1)) * 64;           // XCD-fixed 128-col slice
        const int mb = (loc >> 1) * 128 + w * 32;            // 64 m-tiles, streamed
        f32x4 acc[2][4] = {};
        const u16* pa0 = g_ctxb + (size_t)(mb + l16) * 1024 + quad * 8;
        const u16* pa1 = pa0 + (size_t)16 * 1024;
        const u16* pw = W + (size_t)(n0 + l16) * sW + quad * 8;
#pragma unroll 2
        for (int k0 = 0; k0 < 1024; k0 += 32) {
            short8 a0 = *(const short8*)(const void*)(pa0 + k0);
            short8 a1 = *(const short8*)(const void*)(pa1 + k0);
#pragma unroll
            for (int j = 0; j < 4; ++j) {
                short8 b = *(const short8*)(const void*)(pw + (size_t)j * 16 * sW + k0);
                acc[0][j] = __builtin_amdgcn_mfma_f32_16x16x32_bf16(a0, b, acc[0][j], 0, 0, 0);
                acc[1][j] = __builtin_amdgcn_mfma_f32_16x16x32_bf16(a1, b, acc[1][j], 0, 0, 0);
            }
        }
#pragma unroll
        for (int i = 0; i < 2; ++i)
#pragma unroll
            for (int j = 0; j < 4; ++j)
#pragma unroll
                for (int r = 0; r < 4; ++r)
                    Out[(size_t)(mb + i * 16 + quad * 4 + r) * 1024 + n0 + j * 16 + l16] =
                        f2b(acc[i][j][r]);
    } else {
        // ---- init (row-permuted; g_inv written by k_prepall's sort section) ----
        int i = (bid - 2048) * 256 + tid;    // i < BH_
        int b = i >> 10, h = i & 1023;
        int r = g_inv[b];
        g_XA[0][(size_t)r * KA_ + 1280 + h] = f2b(h0[i]);        // h0 layer0 state
        g_XB[0][(size_t)r * KB_ + 1024 + h] = f2b(h0[BH_ + i]);  // h layer1 state
        g_XC[r * 1024 + h] = f2b(c0[BH_ + i]);                   // initial query c0[-1]
        g_cs0[r * 1024 + h] = c0[i];
        g_cs1[r * 1024 + h] = c0[BH_ + i];
        if (i < BZ_) {
            int bb = i >> 8, z = i & 255;
            g_XA[0][(size_t)g_inv[bb] * KA_ + z] = f2b(z0[i]);
        }
    }
}

__global__ void k_final(float* __restrict__ out) {
    int i = blockIdx.x * 256 + threadIdx.x;  // i < BH_
    int b = i >> 10, h = i & 1023;
    int r = g_inv[b];
    float* hf = out + (size_t)3 * BKZ_;
    float* cf = hf + 2 * BH_;
    hf[i] = b2f(g_XA[0][(size_t)r * KA_ + 1280 + h]);
    hf[BH_ + i] = b2f(g_XB[0][(size_t)r * KB_ + 1024 + h]);
    cf[i] = g_cs0[r * 1024 + h];
    cf[BH_ + i] = g_cs1[r * 1024 + h];
}

extern "C" void kernel_launch(void* const* d_in, const int* in_sizes, int n_in,
                              void* d_out, int out_size, void* d_ws, size_t ws_size,
                              hipStream_t stream) {
    (void)in_sizes; (void)n_in; (void)out_size; (void)d_ws; (void)ws_size;
    const float* h0 = (const float*)d_in[0];
    const float* c0 = (const float*)d_in[1];
    const float* ctx = (const float*)d_in[2];
    const float* z0 = (const float*)d_in[3];
    const int* kvec = (const int*)d_in[4];
    const float* eps = (const float*)d_in[5];
    const float* Wih0 = (const float*)d_in[6];
    const float* Whh0 = (const float*)d_in[7];
    const float* bih0 = (const float*)d_in[8];
    const float* bhh0 = (const float*)d_in[9];
    const float* Wih1 = (const float*)d_in[10];
    const float* Whh1 = (const float*)d_in[11];
    const float* bih1 = (const float*)d_in[12];
    const float* bhh1 = (const float*)d_in[13];
    const float* Win = (const float*)d_in[14];
    const float* Wout = (const float*)d_in[15];
    const float* muW = (const float*)d_in[16];
    const float* mub = (const float*)d_in[17];
    const float* sgW = (const float*)d_in[18];
    const float* sgb = (const float*)d_in[19];
    float* out = (float*)d_out;

    dim3 blk(256);
    // ---- prep: 2 dispatches total ----
    k_prepall<<<PREPALL_NBLK_, blk, 0, stream>>>(
        Wih0, Whh0, bih0, bhh0, Wih1, Whh1, bih1, bhh1,
        muW, mub, sgW, sgb, Win, Wout, ctx, kvec, out);
    k_gemminit<<<2560, blk, 0, stream>>>(h0, c0, z0);

    // ---- initial attention (q = c0[-1]) ----
    k_mix<<<896, blk, 0, stream>>>(eps, out, 0, 0, 1);        // scores + q-GEMM only
    k_contract<<<512, blk, 0, stream>>>(0, 0);                // attn0 -> XA[0]

    // ---- 48 steps ----
    for (int i = 0; i < K_; ++i) {
        k_lstm<0><<<512, blk, 0, stream>>>(i);
        k_lstm<1><<<512, blk, 0, stream>>>(i);
        const int more = (i + 1 < K_) ? 1 : 0;
        k_mix<<<more ? 896 : 256, blk, 0, stream>>>(eps, out, i, 1, more);
        if (more) k_contract<<<512, blk, 0, stream>>>((i + 1) & 1, i);
    }
    // K_=48 even -> final states in parity-0 buffers
    k_final<<<BH_ / 256, blk, 0, stream>>>(out);
}